// Round 8
// baseline (247.879 us; speedup 1.0000x reference)
//
#include <hip/hip_runtime.h>

typedef __attribute__((ext_vector_type(8))) _Float16 half8;
typedef __attribute__((ext_vector_type(4))) _Float16 half4;
typedef __attribute__((ext_vector_type(4))) float f32x4;

#define MFMA_K32(a, b, c) __builtin_amdgcn_mfma_f32_16x16x32_f16((a), (b), (c), 0, 0, 0)
#define MFMA_K16(a, b, c) __builtin_amdgcn_mfma_f32_16x16x16f16((a), (b), (c), 0, 0, 0)

// async global->LDS, 16B per lane; LDS dest = wave-uniform base + lane*16
__device__ inline void async16(const _Float16* g, _Float16* l) {
    __builtin_amdgcn_global_load_lds(
        (const __attribute__((address_space(1))) void*)g,
        (__attribute__((address_space(3))) void*)l, 16, 0, 0);
}

// ---------------------------------------------------------------------------
// B=32, S=512, Dm=768, H=12, d=64, M=16384.
// probs = (s*0.125+5)^2; probs /= (rowsum+1e-10); probs *= mask; ctx = probs@V
// Folded: ctx = (sum_k w_k * (mask_k v_k)) / (sum_k w_k + 1e-10)
// Q is pre-scaled by 0.125 at the GEMM epilogue, so attn uses s = q.k + 5.
// ---------------------------------------------------------------------------

// Kernel 0: fused prep — X f32->f16 cast (blocks 0..6143) and weight
// transpose+cast (blocks 6144..7871).  One launch instead of two.
__global__ __launch_bounds__(256) void prep_kernel(
    const float* __restrict__ X, _Float16* __restrict__ Xh,
    const float* __restrict__ W0, const float* __restrict__ W1,
    const float* __restrict__ W2,
    _Float16* __restrict__ T0, _Float16* __restrict__ T1,
    _Float16* __restrict__ T2)
{
    __shared__ float tile[32][33];
    int bid = blockIdx.x;
    if (bid < 6144) {
        size_t idx = ((size_t)bid * 256 + threadIdx.x) * 8;
        float4 a = *(const float4*)(X + idx);
        float4 c = *(const float4*)(X + idx + 4);
        half8 hv;
        hv[0] = (_Float16)a.x; hv[1] = (_Float16)a.y;
        hv[2] = (_Float16)a.z; hv[3] = (_Float16)a.w;
        hv[4] = (_Float16)c.x; hv[5] = (_Float16)c.y;
        hv[6] = (_Float16)c.z; hv[7] = (_Float16)c.w;
        *(half8*)(Xh + idx) = hv;
    } else {
        int id = bid - 6144;                 // 1728 = 3 x 24 x 24
        int z = id / 576; id -= z * 576;
        int n0 = (id / 24) * 32, k0 = (id % 24) * 32;
        const float* W = (z == 0) ? W0 : (z == 1) ? W1 : W2;
        _Float16* T = (z == 0) ? T0 : (z == 1) ? T1 : T2;
        int tx = threadIdx.x & 31, ty = threadIdx.x >> 5;
#pragma unroll
        for (int r = 0; r < 4; ++r)
            tile[ty + 8 * r][tx] = W[(size_t)(k0 + ty + 8 * r) * 768 + n0 + tx];
        __syncthreads();
#pragma unroll
        for (int r = 0; r < 4; ++r)
            T[(size_t)(n0 + ty + 8 * r) * 768 + k0 + tx] =
                (_Float16)tile[tx][ty + 8 * r];
    }
}

// ---------------------------------------------------------------------------
// Kernel 2: fused QKV GEMM, C[16384 x 2304] over z = n/768.
// 128x128 tile, 256 thr.  2-phase double-buffered K-loop at BK=32.
//
// ROUND-7 POST-MORTEM: dropping the swizzle at BK=32 was wrong —
// SQ_LDS_BANK_CONFLICT hit 7.08M.  At BK=32 a row = 64 B = 16 banks, so a
// quad's 16 lanes (same quad-offset, different rows) hit bank 16*(row&1)+
// quad*4 -> only 2 bank-groups -> 8-way conflict per ds_read_b128.
//
// THIS ROUND: correct swizzle for 64-B rows.  Store global chunk g of row r
// at LDS slot g ^ ((r>>1)&3); read slot = quad ^ ((r>>1)&3).  Group index
// (4*(row&1) + slot) mod 8 then covers all 8 bank-groups twice per quad ->
// 2-way (free, m136).  Key invariances: (r+64)>>1 == r>>1 mod 4 (one XOR key
// serves both STAGE halves) and wm/i*16 are ≡0 mod 4 after >>1 (read key =
// (l16>>1)&3, loop-invariant).  Coalescing unchanged: each 4-thread group
// still fetches a permuted full 64-B row segment.
// Issue-early structure kept: STAGE(buf^1,kt+1) BEFORE compute, one barrier
// per iter -> pre-barrier vmcnt drain waits on loads issued ~400+ cyc ago.
// LDS 2x(8+8)=32 KB -> 4 blocks/CU co-residency preserved.
//
// Epilogue (round-4, kept): operand-role swap for z<2 computes C^T so reg r
// packs over d -> half4 stores; WRITE_SIZE 103->88 MB measured.
// Q out pre-scaled 0.125. V out transposed [B,H,64,S], premasked.
// NOTE: no launch_bounds min-waves arg (round-5: forcing 5/EU spilled acc).
// ---------------------------------------------------------------------------
__global__ __launch_bounds__(256) void qkv_gemm(
    const _Float16* __restrict__ Xh,
    const _Float16* __restrict__ W0, const _Float16* __restrict__ W1,
    const _Float16* __restrict__ W2,
    const float* __restrict__ b0, const float* __restrict__ b1,
    const float* __restrict__ b2,
    const float* __restrict__ mask,
    _Float16* __restrict__ Qo, _Float16* __restrict__ Ko,
    _Float16* __restrict__ Vo)
{
    int z = blockIdx.y / 6;
    int n0 = (blockIdx.y % 6) * 128;
    int m0 = blockIdx.x * 128;
    const _Float16* Wt = (z == 0) ? W0 : (z == 1) ? W1 : W2;
    const float* bias = (z == 0) ? b0 : (z == 1) ? b1 : b2;

    __shared__ __attribute__((aligned(16))) _Float16 As[2 * 4096];  // 16 KB
    __shared__ __attribute__((aligned(16))) _Float16 Bs[2 * 4096];  // 16 KB

    int t = threadIdx.x;
    int wave = t >> 6, lane = t & 63, quad = lane >> 4, l16 = lane & 15;
    int wm = (wave & 1) * 64, wn = (wave >> 1) * 64;

    // staging: thread t -> row tr4 = t>>2 (2nd call: +64, same XOR key since
    // 64>>1 ≡ 0 mod 4), LDS slot t&3, global chunk sg = (t&3) ^ ((tr4>>1)&3).
    int tr4 = t >> 2;
    int sg = (t & 3) ^ ((tr4 >> 1) & 3);
    const _Float16* gA = Xh + (size_t)(m0 + tr4) * 768 + sg * 8;
    const _Float16* gB = Wt + (size_t)(n0 + tr4) * 768 + sg * 8;
    _Float16* lA = As + t * 8;
    _Float16* lB = Bs + t * 8;

#define STAGE(buf, k0v) do {                                          \
        async16(gA + (k0v),              lA + (buf) * 4096);          \
        async16(gA + 64 * 768 + (k0v),   lA + (buf) * 4096 + 2048);   \
        async16(gB + (k0v),              lB + (buf) * 4096);          \
        async16(gB + 64 * 768 + (k0v),   lB + (buf) * 4096 + 2048); } while (0)

    // operand-role swap: for z<2, C rows = W-dim (so r packs over d at the
    // store); for z==2 keep C rows = token (V wants [d][token] with r=token).
    const _Float16* Pa = (z == 2) ? As : Bs;   // feeds af (C rows)
    const _Float16* Pb = (z == 2) ? Bs : As;   // feeds bf (C cols)

    // fragment read slot: quad ^ ((row>>1)&3); row = wm|wn + i*16 + l16 and
    // wm/wn/i*16 vanish mod 4 after >>1 -> key depends only on l16.
    int rk = (l16 >> 1) & 3;
    int slot = (quad ^ rk) * 8;

    f32x4 acc[4][4] = {};

    // prologue: tile 0 -> buf 0 (barrier drains vmcnt)
    STAGE(0, 0);
    __syncthreads();

    for (int kt = 0; kt < 24; ++kt) {
        int c = kt & 1;
        if (kt < 23) STAGE(c ^ 1, (kt + 1) * 32);   // issue-early (T14/T3)

        half8 af[4], bf[4];
#pragma unroll
        for (int i = 0; i < 4; ++i)
            af[i] = *(const half8*)&Pa[c * 4096 + (wm + i * 16 + l16) * 32 + slot];
#pragma unroll
        for (int j = 0; j < 4; ++j)
            bf[j] = *(const half8*)&Pb[c * 4096 + (wn + j * 16 + l16) * 32 + slot];
#pragma unroll
        for (int i = 0; i < 4; ++i)
#pragma unroll
            for (int j = 0; j < 4; ++j)
                acc[i][j] = MFMA_K32(af[i], bf[j], acc[i][j]);

        __syncthreads();  // drains vmcnt (issued ~400+ cyc ago -> covered) and
                          // publishes buf(c^1); reads of buf(c) done before
                          // kt+1 restages it
    }
#undef STAGE

    if (z != 2) {
        // C^T: row = n-dim = n0 + wm + i*16 + quad*4 + r (4 consecutive d,
        // head-aligned since quad*4+r < 16); col = token = m0 + wn + j*16 + l16.
#pragma unroll
        for (int i = 0; i < 4; ++i) {
            int nbase = n0 + wm + i * 16 + quad * 4;
            int hh = nbase >> 6, dbase = nbase & 63;
            float4 bv4 = *(const float4*)&bias[nbase];
#pragma unroll
            for (int j = 0; j < 4; ++j) {
                int token = m0 + wn + j * 16 + l16;
                int bb = token >> 9, s = token & 511;
                half4 pk;
                if (z == 0) {
#pragma unroll
                    for (int r = 0; r < 4; ++r)
                        pk[r] = (_Float16)((acc[i][j][r] + ((const float*)&bv4)[r]) * 0.125f);
                } else {
#pragma unroll
                    for (int r = 0; r < 4; ++r)
                        pk[r] = (_Float16)(acc[i][j][r] + ((const float*)&bv4)[r]);
                }
                size_t off = (((size_t)(bb * 12 + hh)) * 512 + s) * 64 + dbase;
                if (z == 0) *(half4*)&Qo[off] = pk;
                else        *(half4*)&Ko[off] = pk;
            }
        }
    } else {
        // V (unswapped): row = token = m0+wm+i*16+quad*4+r, col = n0+wn+j*16+l16
        float mk[4][4];
#pragma unroll
        for (int i = 0; i < 4; ++i) {
            int mbase = m0 + wm + i * 16 + quad * 4;
            int bb = mbase >> 9, s = mbase & 511;
#pragma unroll
            for (int r = 0; r < 4; ++r)
                mk[i][r] = mask[(size_t)bb * 512 + s + r];
        }
#pragma unroll
        for (int j = 0; j < 4; ++j) {
            int n = n0 + wn + j * 16 + l16;
            float bv = bias[n];
            int hh = n >> 6, d = n & 63;
#pragma unroll
            for (int i = 0; i < 4; ++i) {
                int mbase = m0 + wm + i * 16 + quad * 4;
                int bb = mbase >> 9, s = mbase & 511;
                // V^T [B,H,64,S], premasked; regs = consecutive tokens -> 8B store
                half4 pk;
#pragma unroll
                for (int r = 0; r < 4; ++r)
                    pk[r] = (_Float16)((acc[i][j][r] + bv) * mk[i][r]);
                size_t off = (((size_t)(bb * 12 + hh)) * 64 + d) * 512 + s;
                *(half4*)&Vo[off] = pk;
            }
        }
    }
}

// ---------------------------------------------------------------------------
// Kernel 3: power-law attention, P-in-registers — reg-staged double buffer
// (round-2 variant, best measured; DMA-staged rewrite regressed 5 µs).
// Block = 4 waves x 64 queries (256 q), grid (2, H, B) = 768 blocks
// (3 blocks/CU resident: LDS 45 KB; 12 waves/CU; ALL blocks co-resident).
// 2-deep LDS buffers; next tile's global loads ISSUE before compute,
// LDS write lands after compute (vmcnt hidden under ~1300 cyc of MFMA);
// ONE barrier per tile (write(t+1) targets the other buffer than compute(t)).
// Per 64-key tile: S^T = K Q^T via 16x16x32 MFMA (C: row=key, col=query).
//   Lane holds P[q=l16][k=quad*4+r] == A-fragment of 16x16x16 f16 MFMA.
//   rowsum via MFMA with ones B-frag; ctx += P @ V via 16x16x16 MFMA.
// V premasked; rowsum over unmasked w == reference semantics.
// ---------------------------------------------------------------------------
__global__ __launch_bounds__(256) void attn_kernel(
    const _Float16* __restrict__ Q, const _Float16* __restrict__ K,
    const _Float16* __restrict__ Vt, float* __restrict__ out)
{
    __shared__ __attribute__((aligned(16))) _Float16 Ks[2][64 * 88];  // 22.5 KB
    __shared__ __attribute__((aligned(16))) _Float16 Vs[2][64 * 88];  // 22.5 KB

    int t = threadIdx.x;
    int wave = t >> 6, lane = t & 63, quad = lane >> 4, l16 = lane & 15;
    int h = blockIdx.y, b = blockIdx.z;
    size_t bh = (size_t)b * 12 + h;
    const _Float16* Qp = Q + bh * (512 * 64);
    const _Float16* Kp = K + bh * (512 * 64);
    const _Float16* Vp = Vt + bh * (64 * 512);
    int qbase = blockIdx.x * 256 + wave * 64;

    // Q fragments (B-operand layout == row-major half8 at [query][d])
    half8 qf[4][2];
#pragma unroll
    for (int i = 0; i < 4; ++i)
#pragma unroll
        for (int ks = 0; ks < 2; ++ks)
            qf[i][ks] = *(const half8*)(Qp + (size_t)(qbase + i * 16 + l16) * 64 +
                                        ks * 32 + quad * 8);

    f32x4 ctx[4][4] = {};
    f32x4 rsum[4] = {};
    const half4 ones = {(_Float16)1.f, (_Float16)1.f, (_Float16)1.f, (_Float16)1.f};

    int srow = t >> 2, spart = (t & 3) * 16;  // 4 threads/row, 16 halves each
    const _Float16* kgb = Kp + (size_t)srow * 64 + spart;   // + kt*64*64
    const _Float16* vgb = Vp + (size_t)srow * 512 + spart;  // + kt*64

    // prologue: tile 0 -> buf 0
    half8 ka0 = *(const half8*)(kgb);
    half8 ka1 = *(const half8*)(kgb + 8);
    half8 va0 = *(const half8*)(vgb);
    half8 va1 = *(const half8*)(vgb + 8);
    *(half8*)&Ks[0][srow * 88 + spart] = ka0;
    *(half8*)&Ks[0][srow * 88 + spart + 8] = ka1;
    *(half8*)&Vs[0][srow * 88 + spart] = va0;
    *(half8*)&Vs[0][srow * 88 + spart + 8] = va1;
    __syncthreads();

    for (int kt = 0; kt < 8; ++kt) {
        int c = kt & 1;
        if (kt < 7) {
            // issue next tile's loads NOW; their vmcnt-wait sits after compute
            size_t ko = (size_t)(kt + 1) * 64;
            ka0 = *(const half8*)(kgb + ko * 64);
            ka1 = *(const half8*)(kgb + ko * 64 + 8);
            va0 = *(const half8*)(vgb + ko);
            va1 = *(const half8*)(vgb + ko + 8);
        }

        __builtin_amdgcn_s_setprio(1);
#pragma unroll
        for (int kb = 0; kb < 4; ++kb) {
            half8 kf0 = *(const half8*)&Ks[c][(kb * 16 + l16) * 88 + quad * 8];
            half8 kf1 = *(const half8*)&Ks[c][(kb * 16 + l16) * 88 + 32 + quad * 8];
            // phase A: all QK^T MFMAs (independent chains across i)
            f32x4 sc[4];
#pragma unroll
            for (int i = 0; i < 4; ++i) {
                f32x4 s0 = {0.f, 0.f, 0.f, 0.f};
                s0 = MFMA_K32(kf0, qf[i][0], s0);
                sc[i] = MFMA_K32(kf1, qf[i][1], s0);
            }
            // phase B: VALU transform  w = (s+5)^2  (Q pre-scaled by 0.125)
            half4 pA[4];
#pragma unroll
            for (int i = 0; i < 4; ++i) {
#pragma unroll
                for (int r = 0; r < 4; ++r) {
                    float s = sc[i][r] + 5.0f;
                    pA[i][r] = (_Float16)(s * s);
                }
            }
            // phase C: rowsum MFMAs
#pragma unroll
            for (int i = 0; i < 4; ++i)
                rsum[i] = MFMA_K16(pA[i], ones, rsum[i]);
            // phase D: PV
#pragma unroll
            for (int n = 0; n < 4; ++n) {
                half4 vf = *(const half4*)&Vs[c][(n * 16 + l16) * 88 + kb * 16 + quad * 4];
#pragma unroll
                for (int i = 0; i < 4; ++i)
                    ctx[i][n] = MFMA_K16(pA[i], vf, ctx[i][n]);
            }
        }
        __builtin_amdgcn_s_setprio(0);

        if (kt < 7) {
            // write-late: loads issued ~1300 cycles ago -> vmcnt wait is free
            *(half8*)&Ks[1 - c][srow * 88 + spart] = ka0;
            *(half8*)&Ks[1 - c][srow * 88 + spart + 8] = ka1;
            *(half8*)&Vs[1 - c][srow * 88 + spart] = va0;
            *(half8*)&Vs[1 - c][srow * 88 + spart + 8] = va1;
        }
        __syncthreads();  // single barrier per tile: buf(1-c) writes published,
                          // and all waves done reading buf(c) before it's
                          // overwritten in iteration kt+2
    }

    // epilogue: rsum reg r and ctx reg r both live on C row = quad*4+r
#pragma unroll
    for (int i = 0; i < 4; ++i) {
        f32x4 inv;
#pragma unroll
        for (int r = 0; r < 4; ++r)
            inv[r] = 1.0f / (rsum[i][r] + 1e-10f);
#pragma unroll
        for (int n = 0; n < 4; ++n)
#pragma unroll
            for (int r = 0; r < 4; ++r) {
                int q = qbase + i * 16 + quad * 4 + r;
                int d = n * 16 + l16;
                out[((size_t)b * 512 + q) * 768 + h * 64 + d] =
                    ctx[i][n][r] * inv[r];
            }
    }
}

// ---------------------------------------------------------------------------
extern "C" void kernel_launch(void* const* d_in, const int* in_sizes, int n_in,
                              void* d_out, int out_size, void* d_ws, size_t ws_size,
                              hipStream_t stream)
{
    const float* hs   = (const float*)d_in[0];
    const float* mask = (const float*)d_in[1];
    const float* Wq   = (const float*)d_in[2];
    const float* bq   = (const float*)d_in[3];
    const float* Wk   = (const float*)d_in[4];
    const float* bk   = (const float*)d_in[5];
    const float* Wv   = (const float*)d_in[6];
    const float* bv   = (const float*)d_in[7];
    float* out = (float*)d_out;

    char* ws = (char*)d_ws;
    _Float16* Wtq = (_Float16*)ws;            // 3 x 768*768 halves
    _Float16* Wtk = Wtq + 768 * 768;
    _Float16* Wtv = Wtk + 768 * 768;
    _Float16* Qb  = Wtv + 768 * 768;          // 3 x 16384*768 halves
    _Float16* Kb  = Qb + 16384 * 768;
    _Float16* Vb  = Kb + 16384 * 768;
    // ws use ~79 MB. Xh scratch lives in d_out (Xh 25 MB, dead before attn).
    _Float16* Xh = (_Float16*)d_out;

    prep_kernel<<<dim3(7872), 256, 0, stream>>>(hs, Xh, Wq, Wk, Wv,
                                                Wtq, Wtk, Wtv);
    qkv_gemm<<<dim3(128, 18), 256, 0, stream>>>(Xh, Wtq, Wtk, Wtv,
                                                bq, bk, bv, mask, Qb, Kb, Vb);
    attn_kernel<<<dim3(2, 12, 32), 256, 0, stream>>>(Qb, Kb, Vb, out);
}

// Round 9
// 239.522 us; speedup vs baseline: 1.0349x; 1.0349x over previous
//
#include <hip/hip_runtime.h>

typedef __attribute__((ext_vector_type(8))) _Float16 half8;
typedef __attribute__((ext_vector_type(4))) _Float16 half4;
typedef __attribute__((ext_vector_type(4))) float f32x4;

#define MFMA_K32(a, b, c) __builtin_amdgcn_mfma_f32_16x16x32_f16((a), (b), (c), 0, 0, 0)
#define MFMA_K16(a, b, c) __builtin_amdgcn_mfma_f32_16x16x16f16((a), (b), (c), 0, 0, 0)

// async global->LDS, 16B per lane; LDS dest = wave-uniform base + lane*16
__device__ inline void async16(const _Float16* g, _Float16* l) {
    __builtin_amdgcn_global_load_lds(
        (const __attribute__((address_space(1))) void*)g,
        (__attribute__((address_space(3))) void*)l, 16, 0, 0);
}

// ---------------------------------------------------------------------------
// B=32, S=512, Dm=768, H=12, d=64, M=16384.
// probs = (s*0.125+5)^2; probs /= (rowsum+1e-10); probs *= mask; ctx = probs@V
// Folded: ctx = (sum_k w_k * (mask_k v_k)) / (sum_k w_k + 1e-10)
// Q is pre-scaled by 0.125 at the GEMM epilogue, so attn uses s = q.k + 5.
// ---------------------------------------------------------------------------

// Kernel 0: fused prep — X f32->f16 cast (blocks 0..6143) and weight
// transpose+cast (blocks 6144..7871).  One launch instead of two.
__global__ __launch_bounds__(256) void prep_kernel(
    const float* __restrict__ X, _Float16* __restrict__ Xh,
    const float* __restrict__ W0, const float* __restrict__ W1,
    const float* __restrict__ W2,
    _Float16* __restrict__ T0, _Float16* __restrict__ T1,
    _Float16* __restrict__ T2)
{
    __shared__ float tile[32][33];
    int bid = blockIdx.x;
    if (bid < 6144) {
        size_t idx = ((size_t)bid * 256 + threadIdx.x) * 8;
        float4 a = *(const float4*)(X + idx);
        float4 c = *(const float4*)(X + idx + 4);
        half8 hv;
        hv[0] = (_Float16)a.x; hv[1] = (_Float16)a.y;
        hv[2] = (_Float16)a.z; hv[3] = (_Float16)a.w;
        hv[4] = (_Float16)c.x; hv[5] = (_Float16)c.y;
        hv[6] = (_Float16)c.z; hv[7] = (_Float16)c.w;
        *(half8*)(Xh + idx) = hv;
    } else {
        int id = bid - 6144;                 // 1728 = 3 x 24 x 24
        int z = id / 576; id -= z * 576;
        int n0 = (id / 24) * 32, k0 = (id % 24) * 32;
        const float* W = (z == 0) ? W0 : (z == 1) ? W1 : W2;
        _Float16* T = (z == 0) ? T0 : (z == 1) ? T1 : T2;
        int tx = threadIdx.x & 31, ty = threadIdx.x >> 5;
#pragma unroll
        for (int r = 0; r < 4; ++r)
            tile[ty + 8 * r][tx] = W[(size_t)(k0 + ty + 8 * r) * 768 + n0 + tx];
        __syncthreads();
#pragma unroll
        for (int r = 0; r < 4; ++r)
            T[(size_t)(n0 + ty + 8 * r) * 768 + k0 + tx] =
                (_Float16)tile[tx][ty + 8 * r];
    }
}

// ---------------------------------------------------------------------------
// Kernel 2: fused QKV GEMM, C[16384 x 2304] over z = n/768.
// 128x128 tile, 256 thr, BK=64 (round-4 geometry + swizzle, proven 93 µs).
//
// THIS ROUND: counted-vmcnt double buffer (T4 proper).  Rounds 6-8 never
// tested T4: their loop ended in __syncthreads(), which drains vmcnt(0)
// INCLUDING the just-issued prefetch -> zero latency distance gained.
// Now: STAGE(buf^1, kt+1) -> s_waitcnt vmcnt(8) (waits ONLY for the previous
// iteration's 8 loads, issued a full iteration ago; the fresh 8 stay in
// flight across the barrier) -> raw s_barrier -> ds_read+MFMA -> raw barrier.
// Tail drains vmcnt(0) only at kt=11.  FIFO vmcnt retirement (m135) makes
// any hoisted unrelated load an over-wait (safe); "memory" clobbers pin the
// async16s on both sides of the waits; sched_barrier(0) pins ds_reads
// inside the barrier pair (rule #18).
// LDS 2x(16+16) = 64 KB -> 2 blocks/CU (8 waves).  Trade: half the waves of
// round-4, but the per-iter latency wall (~2100 cyc measured) should fall to
// the throughput floor if the pipeline holds.
// XOR swizzle unchanged: LDS chunk j of row r holds global chunk j^(r&7);
// readers use slot = ((ks<<2)+quad) ^ (row&7) -> 2-way (free), round-4
// measured 0 conflicts.
//
// Epilogue (round-4, kept): operand-role swap for z<2 computes C^T so reg r
// packs over d -> half4 stores; WRITE_SIZE 103->88 MB measured.
// Q out pre-scaled 0.125. V out transposed [B,H,64,S], premasked.
// NOTE: no launch_bounds min-waves arg (round-5: forcing 5/EU spilled acc).
// ---------------------------------------------------------------------------
__global__ __launch_bounds__(256) void qkv_gemm(
    const _Float16* __restrict__ Xh,
    const _Float16* __restrict__ W0, const _Float16* __restrict__ W1,
    const _Float16* __restrict__ W2,
    const float* __restrict__ b0, const float* __restrict__ b1,
    const float* __restrict__ b2,
    const float* __restrict__ mask,
    _Float16* __restrict__ Qo, _Float16* __restrict__ Ko,
    _Float16* __restrict__ Vo)
{
    int z = blockIdx.y / 6;
    int n0 = (blockIdx.y % 6) * 128;
    int m0 = blockIdx.x * 128;
    const _Float16* Wt = (z == 0) ? W0 : (z == 1) ? W1 : W2;
    const float* bias = (z == 0) ? b0 : (z == 1) ? b1 : b2;

    __shared__ __attribute__((aligned(16))) _Float16 As[2 * 8192];  // 32 KB
    __shared__ __attribute__((aligned(16))) _Float16 Bs[2 * 8192];  // 32 KB

    int t = threadIdx.x;
    int wave = t >> 6, lane = t & 63, quad = lane >> 4, l16 = lane & 15;
    int wm = (wave & 1) * 64, wn = (wave >> 1) * 64;

    // staging: chunk index c = slot*256 + t; row = c>>3, LDS slot j = c&7,
    // global chunk g = j ^ (row&7).  (slot*256 doesn't change row&7 or j.)
    int srow = t >> 3;               // 0..31 (row advances +32 per slot)
    int sg = (t & 7) ^ (srow & 7);   // global chunk this thread fetches

    const _Float16* gA = Xh + (size_t)(m0 + srow) * 768 + sg * 8;
    const _Float16* gB = Wt + (size_t)(n0 + srow) * 768 + sg * 8;
    _Float16* lA = As + t * 8;
    _Float16* lB = Bs + t * 8;

#define STAGE(buf, k0v) do {                                                   \
        async16(gA,                    lA + (buf) * 8192);                     \
        async16(gA + (size_t)1 * 32 * 768 + (k0v) - (k0v) + (k0v), lA + (buf) * 8192 + 2048); \
        async16(gA + (size_t)2 * 32 * 768 + (k0v), lA + (buf) * 8192 + 4096);  \
        async16(gA + (size_t)3 * 32 * 768 + (k0v), lA + (buf) * 8192 + 6144);  \
        async16(gB + (k0v),            lB + (buf) * 8192);                     \
        async16(gB + (size_t)1 * 32 * 768 + (k0v), lB + (buf) * 8192 + 2048);  \
        async16(gB + (size_t)2 * 32 * 768 + (k0v), lB + (buf) * 8192 + 4096);  \
        async16(gB + (size_t)3 * 32 * 768 + (k0v), lB + (buf) * 8192 + 6144); } while (0)
#undef STAGE
#define STAGE(buf, k0v) do {                                                   \
        async16(gA + (k0v),                        lA + (buf) * 8192);         \
        async16(gA + (size_t)1 * 32 * 768 + (k0v), lA + (buf) * 8192 + 2048);  \
        async16(gA + (size_t)2 * 32 * 768 + (k0v), lA + (buf) * 8192 + 4096);  \
        async16(gA + (size_t)3 * 32 * 768 + (k0v), lA + (buf) * 8192 + 6144);  \
        async16(gB + (k0v),                        lB + (buf) * 8192);         \
        async16(gB + (size_t)1 * 32 * 768 + (k0v), lB + (buf) * 8192 + 2048);  \
        async16(gB + (size_t)2 * 32 * 768 + (k0v), lB + (buf) * 8192 + 4096);  \
        async16(gB + (size_t)3 * 32 * 768 + (k0v), lB + (buf) * 8192 + 6144); } while (0)

    // operand-role swap: for z<2, C rows = W-dim (so r packs over d at the
    // store); for z==2 keep C rows = token (V wants [d][token] with r=token).
    const _Float16* Pa = (z == 2) ? As : Bs;   // feeds af (C rows)
    const _Float16* Pb = (z == 2) ? Bs : As;   // feeds bf (C cols)

    f32x4 acc[4][4] = {};

    // prologue: tile 0 -> buf 0 (8 loads in flight; first body wait covers)
    STAGE(0, 0);

    for (int kt = 0; kt < 12; ++kt) {
        int c = kt & 1;
        if (kt < 11) {
            STAGE(c ^ 1, (kt + 1) * 64);
            // counted wait: only the PREVIOUS iteration's 8 loads (issued a
            // full iteration ago) must have landed; the fresh 8 stay in flight
            asm volatile("s_waitcnt vmcnt(8)" ::: "memory");
        } else {
            asm volatile("s_waitcnt vmcnt(0)" ::: "memory");
        }
        __builtin_amdgcn_s_barrier();
        __builtin_amdgcn_sched_barrier(0);   // pin ds_reads below the barrier

        const _Float16* Pa_ = Pa + c * 8192;
        const _Float16* Pb_ = Pb + c * 8192;
#pragma unroll
        for (int ks = 0; ks < 2; ++ks) {
            half8 af[4], bf[4];
#pragma unroll
            for (int i = 0; i < 4; ++i) {
                int row = wm + i * 16 + l16;
                af[i] = *(const half8*)&Pa_[row * 64 +
                                            (((ks << 2) + quad) ^ (row & 7)) * 8];
            }
#pragma unroll
            for (int j = 0; j < 4; ++j) {
                int row = wn + j * 16 + l16;
                bf[j] = *(const half8*)&Pb_[row * 64 +
                                            (((ks << 2) + quad) ^ (row & 7)) * 8];
            }
#pragma unroll
            for (int i = 0; i < 4; ++i)
#pragma unroll
                for (int j = 0; j < 4; ++j)
                    acc[i][j] = MFMA_K32(af[i], bf[j], acc[i][j]);
        }
        __builtin_amdgcn_sched_barrier(0);   // pin ds_reads above the barrier
        __builtin_amdgcn_s_barrier();        // all waves done reading buf(c)
                                             // before kt+1 restages it
    }
#undef STAGE

    if (z != 2) {
        // C^T: row = n-dim = n0 + wm + i*16 + quad*4 + r (4 consecutive d,
        // head-aligned since quad*4+r < 16); col = token = m0 + wn + j*16 + l16.
#pragma unroll
        for (int i = 0; i < 4; ++i) {
            int nbase = n0 + wm + i * 16 + quad * 4;
            int hh = nbase >> 6, dbase = nbase & 63;
            float4 bv4 = *(const float4*)&bias[nbase];
#pragma unroll
            for (int j = 0; j < 4; ++j) {
                int token = m0 + wn + j * 16 + l16;
                int bb = token >> 9, s = token & 511;
                half4 pk;
                if (z == 0) {
#pragma unroll
                    for (int r = 0; r < 4; ++r)
                        pk[r] = (_Float16)((acc[i][j][r] + ((const float*)&bv4)[r]) * 0.125f);
                } else {
#pragma unroll
                    for (int r = 0; r < 4; ++r)
                        pk[r] = (_Float16)(acc[i][j][r] + ((const float*)&bv4)[r]);
                }
                size_t off = (((size_t)(bb * 12 + hh)) * 512 + s) * 64 + dbase;
                if (z == 0) *(half4*)&Qo[off] = pk;
                else        *(half4*)&Ko[off] = pk;
            }
        }
    } else {
        // V (unswapped): row = token = m0+wm+i*16+quad*4+r, col = n0+wn+j*16+l16
        float mk[4][4];
#pragma unroll
        for (int i = 0; i < 4; ++i) {
            int mbase = m0 + wm + i * 16 + quad * 4;
            int bb = mbase >> 9, s = mbase & 511;
#pragma unroll
            for (int r = 0; r < 4; ++r)
                mk[i][r] = mask[(size_t)bb * 512 + s + r];
        }
#pragma unroll
        for (int j = 0; j < 4; ++j) {
            int n = n0 + wn + j * 16 + l16;
            float bv = bias[n];
            int hh = n >> 6, d = n & 63;
#pragma unroll
            for (int i = 0; i < 4; ++i) {
                int mbase = m0 + wm + i * 16 + quad * 4;
                int bb = mbase >> 9, s = mbase & 511;
                // V^T [B,H,64,S], premasked; regs = consecutive tokens -> 8B store
                half4 pk;
#pragma unroll
                for (int r = 0; r < 4; ++r)
                    pk[r] = (_Float16)((acc[i][j][r] + bv) * mk[i][r]);
                size_t off = (((size_t)(bb * 12 + hh)) * 64 + d) * 512 + s;
                *(half4*)&Vo[off] = pk;
            }
        }
    }
}

// ---------------------------------------------------------------------------
// Kernel 3: power-law attention, P-in-registers — reg-staged double buffer
// (round-2 variant, best measured; DMA-staged rewrite regressed 5 µs).
// Block = 4 waves x 64 queries (256 q), grid (2, H, B) = 768 blocks
// (3 blocks/CU resident: LDS 45 KB; 12 waves/CU; ALL blocks co-resident).
// 2-deep LDS buffers; next tile's global loads ISSUE before compute,
// LDS write lands after compute (vmcnt hidden under ~1300 cyc of MFMA);
// ONE barrier per tile (write(t+1) targets the other buffer than compute(t)).
// Per 64-key tile: S^T = K Q^T via 16x16x32 MFMA (C: row=key, col=query).
//   Lane holds P[q=l16][k=quad*4+r] == A-fragment of 16x16x16 f16 MFMA.
//   rowsum via MFMA with ones B-frag; ctx += P @ V via 16x16x16 MFMA.
// V premasked; rowsum over unmasked w == reference semantics.
// ---------------------------------------------------------------------------
__global__ __launch_bounds__(256) void attn_kernel(
    const _Float16* __restrict__ Q, const _Float16* __restrict__ K,
    const _Float16* __restrict__ Vt, float* __restrict__ out)
{
    __shared__ __attribute__((aligned(16))) _Float16 Ks[2][64 * 88];  // 22.5 KB
    __shared__ __attribute__((aligned(16))) _Float16 Vs[2][64 * 88];  // 22.5 KB

    int t = threadIdx.x;
    int wave = t >> 6, lane = t & 63, quad = lane >> 4, l16 = lane & 15;
    int h = blockIdx.y, b = blockIdx.z;
    size_t bh = (size_t)b * 12 + h;
    const _Float16* Qp = Q + bh * (512 * 64);
    const _Float16* Kp = K + bh * (512 * 64);
    const _Float16* Vp = Vt + bh * (64 * 512);
    int qbase = blockIdx.x * 256 + wave * 64;

    // Q fragments (B-operand layout == row-major half8 at [query][d])
    half8 qf[4][2];
#pragma unroll
    for (int i = 0; i < 4; ++i)
#pragma unroll
        for (int ks = 0; ks < 2; ++ks)
            qf[i][ks] = *(const half8*)(Qp + (size_t)(qbase + i * 16 + l16) * 64 +
                                        ks * 32 + quad * 8);

    f32x4 ctx[4][4] = {};
    f32x4 rsum[4] = {};
    const half4 ones = {(_Float16)1.f, (_Float16)1.f, (_Float16)1.f, (_Float16)1.f};

    int srow = t >> 2, spart = (t & 3) * 16;  // 4 threads/row, 16 halves each
    const _Float16* kgb = Kp + (size_t)srow * 64 + spart;   // + kt*64*64
    const _Float16* vgb = Vp + (size_t)srow * 512 + spart;  // + kt*64

    // prologue: tile 0 -> buf 0
    half8 ka0 = *(const half8*)(kgb);
    half8 ka1 = *(const half8*)(kgb + 8);
    half8 va0 = *(const half8*)(vgb);
    half8 va1 = *(const half8*)(vgb + 8);
    *(half8*)&Ks[0][srow * 88 + spart] = ka0;
    *(half8*)&Ks[0][srow * 88 + spart + 8] = ka1;
    *(half8*)&Vs[0][srow * 88 + spart] = va0;
    *(half8*)&Vs[0][srow * 88 + spart + 8] = va1;
    __syncthreads();

    for (int kt = 0; kt < 8; ++kt) {
        int c = kt & 1;
        if (kt < 7) {
            // issue next tile's loads NOW; their vmcnt-wait sits after compute
            size_t ko = (size_t)(kt + 1) * 64;
            ka0 = *(const half8*)(kgb + ko * 64);
            ka1 = *(const half8*)(kgb + ko * 64 + 8);
            va0 = *(const half8*)(vgb + ko);
            va1 = *(const half8*)(vgb + ko + 8);
        }

        __builtin_amdgcn_s_setprio(1);
#pragma unroll
        for (int kb = 0; kb < 4; ++kb) {
            half8 kf0 = *(const half8*)&Ks[c][(kb * 16 + l16) * 88 + quad * 8];
            half8 kf1 = *(const half8*)&Ks[c][(kb * 16 + l16) * 88 + 32 + quad * 8];
            // phase A: all QK^T MFMAs (independent chains across i)
            f32x4 sc[4];
#pragma unroll
            for (int i = 0; i < 4; ++i) {
                f32x4 s0 = {0.f, 0.f, 0.f, 0.f};
                s0 = MFMA_K32(kf0, qf[i][0], s0);
                sc[i] = MFMA_K32(kf1, qf[i][1], s0);
            }
            // phase B: VALU transform  w = (s+5)^2  (Q pre-scaled by 0.125)
            half4 pA[4];
#pragma unroll
            for (int i = 0; i < 4; ++i) {
#pragma unroll
                for (int r = 0; r < 4; ++r) {
                    float s = sc[i][r] + 5.0f;
                    pA[i][r] = (_Float16)(s * s);
                }
            }
            // phase C: rowsum MFMAs
#pragma unroll
            for (int i = 0; i < 4; ++i)
                rsum[i] = MFMA_K16(pA[i], ones, rsum[i]);
            // phase D: PV
#pragma unroll
            for (int n = 0; n < 4; ++n) {
                half4 vf = *(const half4*)&Vs[c][(n * 16 + l16) * 88 + kb * 16 + quad * 4];
#pragma unroll
                for (int i = 0; i < 4; ++i)
                    ctx[i][n] = MFMA_K16(pA[i], vf, ctx[i][n]);
            }
        }
        __builtin_amdgcn_s_setprio(0);

        if (kt < 7) {
            // write-late: loads issued ~1300 cycles ago -> vmcnt wait is free
            *(half8*)&Ks[1 - c][srow * 88 + spart] = ka0;
            *(half8*)&Ks[1 - c][srow * 88 + spart + 8] = ka1;
            *(half8*)&Vs[1 - c][srow * 88 + spart] = va0;
            *(half8*)&Vs[1 - c][srow * 88 + spart + 8] = va1;
        }
        __syncthreads();  // single barrier per tile: buf(1-c) writes published,
                          // and all waves done reading buf(c) before it's
                          // overwritten in iteration kt+2
    }

    // epilogue: rsum reg r and ctx reg r both live on C row = quad*4+r
#pragma unroll
    for (int i = 0; i < 4; ++i) {
        f32x4 inv;
#pragma unroll
        for (int r = 0; r < 4; ++r)
            inv[r] = 1.0f / (rsum[i][r] + 1e-10f);
#pragma unroll
        for (int n = 0; n < 4; ++n)
#pragma unroll
            for (int r = 0; r < 4; ++r) {
                int q = qbase + i * 16 + quad * 4 + r;
                int d = n * 16 + l16;
                out[((size_t)b * 512 + q) * 768 + h * 64 + d] =
                    ctx[i][n][r] * inv[r];
            }
    }
}

// ---------------------------------------------------------------------------
extern "C" void kernel_launch(void* const* d_in, const int* in_sizes, int n_in,
                              void* d_out, int out_size, void* d_ws, size_t ws_size,
                              hipStream_t stream)
{
    const float* hs   = (const float*)d_in[0];
    const float* mask = (const float*)d_in[1];
    const float* Wq   = (const float*)d_in[2];
    const float* bq   = (const float*)d_in[3];
    const float* Wk   = (const float*)d_in[4];
    const float* bk   = (const float*)d_in[5];
    const float* Wv   = (const float*)d_in[6];
    const float* bv   = (const float*)d_in[7];
    float* out = (float*)d_out;

    char* ws = (char*)d_ws;
    _Float16* Wtq = (_Float16*)ws;            // 3 x 768*768 halves
    _Float16* Wtk = Wtq + 768 * 768;
    _Float16* Wtv = Wtk + 768 * 768;
    _Float16* Qb  = Wtv + 768 * 768;          // 3 x 16384*768 halves
    _Float16* Kb  = Qb + 16384 * 768;
    _Float16* Vb  = Kb + 16384 * 768;
    // ws use ~79 MB. Xh scratch lives in d_out (Xh 25 MB, dead before attn).
    _Float16* Xh = (_Float16*)d_out;

    prep_kernel<<<dim3(7872), 256, 0, stream>>>(hs, Xh, Wq, Wk, Wv,
                                                Wtq, Wtk, Wtv);
    qkv_gemm<<<dim3(128, 18), 256, 0, stream>>>(Xh, Wtq, Wtk, Wtv,
                                                bq, bk, bv, mask, Qb, Kb, Vb);
    attn_kernel<<<dim3(2, 12, 32), 256, 0, stream>>>(Qb, Kb, Vb, out);
}